// Round 1
// baseline (943.758 us; speedup 1.0000x reference)
//
#include <hip/hip_runtime.h>

#define HIDDEN 5120
#define NEXP 160
#define CHUNK_BYTES 20480           // per 32-k chunk: 160 rows x 64B hi, then 160 x 64B lo
#define NCHUNK 160                  // 5120 / 32
#define WBYTES (CHUNK_BYTES * NCHUNK)   // 3,276,800 B of converted W in ws

typedef _Float16 f16;
typedef f16 f16x8 __attribute__((ext_vector_type(8)));
typedef float f32x4 __attribute__((ext_vector_type(4)));

__device__ __forceinline__ void async_copy16(const void* g, void* l) {
    __builtin_amdgcn_global_load_lds(
        (const __attribute__((address_space(1))) unsigned int*)g,
        (__attribute__((address_space(3))) unsigned int*)l,
        16, 0, 0);
}

// ---------------- K0: W fp32 -> chunked f16 hi/lo (v = hi + lo/2048) ----------------
__global__ void k_convert_w(const float* __restrict__ W, unsigned char* __restrict__ W2) {
    int t = blockIdx.x * 256 + threadIdx.x;        // 102400 threads, 8 k-elems each
    int e  = t / (HIDDEN / 8);
    int k8 = (t - e * (HIDDEN / 8)) * 8;
    const float* src = W + (long)e * HIDDEN + k8;
    float4 v0 = *(const float4*)(src);
    float4 v1 = *(const float4*)(src + 4);
    float v[8] = {v0.x, v0.y, v0.z, v0.w, v1.x, v1.y, v1.z, v1.w};
    f16x8 hi, lo;
#pragma unroll
    for (int j = 0; j < 8; ++j) {
        f16 h = (f16)v[j];
        hi[j] = h;
        lo[j] = (f16)((v[j] - (float)h) * 2048.0f);
    }
    int kc = k8 >> 5;
    int ko = k8 & 31;
    unsigned char* base = W2 + (size_t)kc * CHUNK_BYTES + e * 64 + ko * 2;
    *(f16x8*)base = hi;
    *(f16x8*)(base + 10240) = lo;
}

// ---------------- K1: counted-vmcnt pipelined split-f16 MFMA GEMM ----------------
// Structure (T3/T4 port): raw s_barrier + s_waitcnt vmcnt(7) — one 7-op group
// (5 global_load_lds + 2 A dwordx4) always in flight; never drained to 0 in the
// main loop.  Group g is issued at end of step g-2 into buf[g&1].
template <int CUR, bool LAST, bool PREFETCH>
__device__ __forceinline__ void gemm_step(
    int kc, const float* aptr, const unsigned char* gstage, unsigned char* lstage,
    unsigned char* ldsbase, int vb, float4& c0, float4& c1,
    f32x4* acc0, f32x4* acc1)
{
    // group kc complete (own lanes), groups kc+1 (and kc+2 in paired steps) stay in flight
    if constexpr (LAST) {
        asm volatile("s_waitcnt vmcnt(0)");
    } else {
        asm volatile("s_waitcnt vmcnt(7)");
    }
    __builtin_amdgcn_sched_barrier(0);
    __builtin_amdgcn_s_barrier();          // everyone's group kc staged; all done reading buf[CUR] from kc-2
    __builtin_amdgcn_sched_barrier(0);

    // convert current A regs -> hi/lo f16 fragments
    float av[8] = {c0.x, c0.y, c0.z, c0.w, c1.x, c1.y, c1.z, c1.w};
    f16x8 ahi, alo;
#pragma unroll
    for (int j = 0; j < 8; ++j) {
        f16 h = (f16)av[j];
        ahi[j] = h;
        alo[j] = (f16)((av[j] - (float)h) * 2048.0f);
    }

    const unsigned char* lb = ldsbase + CUR * CHUNK_BYTES + vb;
    __builtin_amdgcn_s_setprio(1);
#pragma unroll
    for (int n = 0; n < 10; ++n) {
        f16x8 bhi = *(const f16x8*)(lb + n * 1024);
        f16x8 blo = *(const f16x8*)(lb + n * 1024 + 10240);
        acc0[n] = __builtin_amdgcn_mfma_f32_16x16x32_f16(ahi, bhi, acc0[n], 0, 0, 0);
        acc1[n] = __builtin_amdgcn_mfma_f32_16x16x32_f16(alo, bhi, acc1[n], 0, 0, 0);
        acc1[n] = __builtin_amdgcn_mfma_f32_16x16x32_f16(ahi, blo, acc1[n], 0, 0, 0);
    }
    __builtin_amdgcn_s_setprio(0);

    if constexpr (!LAST) {
        __builtin_amdgcn_s_barrier();      // all waves done reading buf[CUR] -> safe to overwrite
        __builtin_amdgcn_sched_barrier(0);
        if constexpr (PREFETCH) {
            const unsigned char* gs = gstage + (size_t)(kc + 2) * CHUNK_BYTES;
            unsigned char* ls = lstage + CUR * CHUNK_BYTES;
#pragma unroll
            for (int i = 0; i < 5; ++i)
                async_copy16(gs + i * 4096, ls + i * 4096);
            c0 = *(const float4*)(aptr + (kc + 2) * 32);
            c1 = *(const float4*)(aptr + (kc + 2) * 32 + 4);
        }
        __builtin_amdgcn_sched_barrier(0);
    }
}

__global__ __launch_bounds__(256, 2)
void k_gemm(const float* __restrict__ X, const unsigned char* __restrict__ W2,
            float* __restrict__ logits) {
    __shared__ __align__(16) unsigned char lds[2 * CHUNK_BYTES];   // 40 KB, double-buffered
    const int tid = threadIdx.x;
    const int w   = tid >> 6;          // wave -> M-tile (16 rows each), BM = 64
    const int l   = tid & 63;
    const int r16 = l & 15;
    const int q   = l >> 4;

    const long rowA = (long)blockIdx.x * 64 + w * 16 + r16;
    const float* aptr = X + rowA * HIDDEN + q * 8;

    const unsigned char* gstage = W2 + (size_t)tid * 16;
    unsigned char* lstage = lds + (tid & ~63) * 16;       // wave-uniform base (+lane*16 by HW)
    const int vb = r16 * 64 + q * 16;                     // B-fragment LDS offset

    f32x4 acc0[10], acc1[10];
    const f32x4 zero = {0.f, 0.f, 0.f, 0.f};
#pragma unroll
    for (int n = 0; n < 10; ++n) { acc0[n] = zero; acc1[n] = zero; }

    // prologue: issue group 0 (buf0) then group 1 (buf1), order pinned
    float4 a00, a01, a10, a11;
#pragma unroll
    for (int i = 0; i < 5; ++i)
        async_copy16(gstage + i * 4096, lstage + i * 4096);
    a00 = *(const float4*)(aptr);
    a01 = *(const float4*)(aptr + 4);
    __builtin_amdgcn_sched_barrier(0);
#pragma unroll
    for (int i = 0; i < 5; ++i)
        async_copy16(gstage + CHUNK_BYTES + i * 4096, lstage + CHUNK_BYTES + i * 4096);
    a10 = *(const float4*)(aptr + 32);
    a11 = *(const float4*)(aptr + 36);
    __builtin_amdgcn_sched_barrier(0);

    for (int kc = 0; kc < NCHUNK - 2; kc += 2) {
        gemm_step<0, false, true>(kc,     aptr, gstage, lstage, lds, vb, a00, a01, acc0, acc1);
        gemm_step<1, false, true>(kc + 1, aptr, gstage, lstage, lds, vb, a10, a11, acc0, acc1);
    }
    gemm_step<0, false, false>(NCHUNK - 2, aptr, gstage, lstage, lds, vb, a00, a01, acc0, acc1);
    gemm_step<1, true,  false>(NCHUNK - 1, aptr, gstage, lstage, lds, vb, a10, a11, acc0, acc1);

    // epilogue: logits = acc0 + acc1/2048.  C/D layout: col=lane&15, row=(lane>>4)*4+reg
    const long rowD = (long)blockIdx.x * 64 + w * 16 + q * 4;
    float* orow = logits + rowD * NEXP + r16;
#pragma unroll
    for (int n = 0; n < 10; ++n) {
#pragma unroll
        for (int rr = 0; rr < 4; ++rr) {
            orow[(long)rr * NEXP + n * 16] = acc0[n][rr] + acc1[n][rr] * (1.0f / 2048.0f);
        }
    }
}

// ---------------- K2: gate, 8 lanes per token (one lane per expert group) ----------------
// 262144 threads = 16 waves/CU (was 2).  Lane sub=l&7 owns group sub's 20 logits.
__global__ __launch_bounds__(256)
void k_gate(const float* __restrict__ logits, float* __restrict__ out) {
    const int t = blockIdx.x * 256 + threadIdx.x;
    const int token = t >> 3;
    const int sub   = t & 7;                       // expert group id
    const float* grp = logits + (long)token * NEXP + sub * 20;

    float v[20];
#pragma unroll
    for (int i = 0; i < 5; ++i) {
        float4 x = *(const float4*)(grp + i * 4);
        v[i * 4 + 0] = x.x; v[i * 4 + 1] = x.y; v[i * 4 + 2] = x.z; v[i * 4 + 3] = x.w;
    }

    float gmax = -1e30f, s = 0.f;
#pragma unroll
    for (int i = 0; i < 20; ++i) {
        gmax = fmaxf(gmax, v[i]);
        s += __expf(v[i]);
    }

    // softmax denom over full row: width-8 shuffle sum
    s += __shfl_xor(s, 1, 8);
    s += __shfl_xor(s, 2, 8);
    s += __shfl_xor(s, 4, 8);
    const float denom = s;

    // top-3 groups by group-max logit; ties -> lower group index (lax.top_k)
    float g = gmax;
    int sel0, sel1, sel2;
#pragma unroll
    for (int r = 0; r < 3; ++r) {
        float bv = g; int bi = sub;
#pragma unroll
        for (int m = 1; m < 8; m <<= 1) {
            float ov = __shfl_xor(bv, m, 8);
            int   oi = __shfl_xor(bi, m, 8);
            if (ov > bv || (ov == bv && oi < bi)) { bv = ov; bi = oi; }
        }
        if (r == 0) sel0 = bi; else if (r == 1) sel1 = bi; else sel2 = bi;
        if (sub == bi) g = -1e30f;                 // knock my group out for next round
    }
    const bool selected = (sub == sel0) | (sub == sel1) | (sub == sel2);

    // per-lane sorted top-6 of my 20 values (desc); non-selected lanes stay at -inf
    float w6[6] = {-1e30f, -1e30f, -1e30f, -1e30f, -1e30f, -1e30f};
    if (selected) {
#pragma unroll
        for (int i = 0; i < 20; ++i) {
            float x = v[i];
            if (x > w6[5]) {
                w6[5] = x;
#pragma unroll
                for (int j = 5; j > 0; --j)
                    if (w6[j] > w6[j - 1]) { float tmp = w6[j - 1]; w6[j - 1] = w6[j]; w6[j] = tmp; }
            }
        }
    }

    // 6-round cross-lane tournament merge; ties -> lower group (lower expert index)
    float res0, res1, res2, res3, res4, res5;
#pragma unroll
    for (int r = 0; r < 6; ++r) {
        float bv = w6[0]; int bi = sub;
#pragma unroll
        for (int m = 1; m < 8; m <<= 1) {
            float ov = __shfl_xor(bv, m, 8);
            int   oi = __shfl_xor(bi, m, 8);
            if (ov > bv || (ov == bv && oi < bi)) { bv = ov; bi = oi; }
        }
        if (r == 0) res0 = bv; else if (r == 1) res1 = bv; else if (r == 2) res2 = bv;
        else if (r == 3) res3 = bv; else if (r == 4) res4 = bv; else res5 = bv;
        if (sub == bi) {                           // winner pops its head (static shifts)
            w6[0] = w6[1]; w6[1] = w6[2]; w6[2] = w6[3];
            w6[3] = w6[4]; w6[4] = w6[5]; w6[5] = -1e30f;
        }
    }

    // lanes 0..5 write result[sub]
    float mine = res0;
    if (sub == 1) mine = res1;
    else if (sub == 2) mine = res2;
    else if (sub == 3) mine = res3;
    else if (sub == 4) mine = res4;
    else if (sub == 5) mine = res5;
    if (sub < 6)
        out[(long)token * 6 + sub] = 16.0f * __expf(mine) / denom;
}

extern "C" void kernel_launch(void* const* d_in, const int* in_sizes, int n_in,
                              void* d_out, int out_size, void* d_ws, size_t ws_size,
                              hipStream_t stream) {
    const float* X = (const float*)d_in[0];        // hidden_states [32768, 5120] fp32
    const float* W = (const float*)d_in[1];        // kernel [160, 5120] fp32
    float* out = (float*)d_out;                    // [32768, 6] fp32

    unsigned char* ws = (unsigned char*)d_ws;
    unsigned char* W2 = ws;                        // 3,276,800 B converted W
    float* logits = (float*)(ws + WBYTES);         // 32768*160*4 = 20,971,520 B

    hipLaunchKernelGGL(k_convert_w, dim3(400),  dim3(256), 0, stream, W, W2);
    hipLaunchKernelGGL(k_gemm,      dim3(512),  dim3(256), 0, stream, X, W2, logits);
    hipLaunchKernelGGL(k_gate,      dim3(1024), dim3(256), 0, stream, logits, out);
}